// Round 2
// baseline (852.755 us; speedup 1.0000x reference)
//
#include <hip/hip_runtime.h>

#define NB      16384
#define QS      1204
#define FD      7
#define ROWF    (QS * FD)     // 8428 floats per batch row
#define NCH     120
#define NOFF    5
#define WINSZ   10
#define CATN    600
#define H1N     128
#define H2N     32
#define OUTN    2
#define G       4             // batch rows per block (one per wave)
#define NTHR    256

__global__ __launch_bounds__(NTHR) void fused_struct3(
    const float* __restrict__ x,
    const float* __restrict__ w_step,
    const float* __restrict__ b_step,
    const float* __restrict__ wA,
    const float* __restrict__ bA,
    const float* __restrict__ wB,
    const float* __restrict__ bB,
    const float* __restrict__ wC,
    const float* __restrict__ bC,
    float* __restrict__ out)
{
    // 31.4 KB total -> 5 blocks/CU (20 waves/CU) on 160 KiB LDS
    __shared__ __align__(16) float orow_s[G][QS];     // 19264 B (dead after pooling; aliased as `red`)
    __shared__ __align__(16) float cat_s[G][CATN];    //  9600 B
    __shared__ __align__(16) float h1_s[G][H1N];      //  2048 B
    __shared__ __align__(16) float h2_s[G][H2N];      //   512 B

    const int t    = threadIdx.x;
    const int lane = t & 63;
    const int w    = t >> 6;          // wave id 0..3 -> row within block
    const int b0   = blockIdx.x * G;

    const float w0 = w_step[0], w1 = w_step[1], w2 = w_step[2], w3 = w_step[3],
                w4 = w_step[4], w5 = w_step[5], w6 = w_step[6];
    const float bs = b_step[0];

    // ---------- Phase 1a: per-wave row dot, straight from global ----------
    {
        const float* row = x + (size_t)(b0 + w) * ROWF;
        for (int q = lane; q < QS; q += 64) {
            const float* p = row + q * FD;
            float s = fmaf(p[0], w0, bs);
            s = fmaf(p[1], w1, s);
            s = fmaf(p[2], w2, s);
            s = fmaf(p[3], w3, s);
            s = fmaf(p[4], w4, s);
            s = fmaf(p[5], w5, s);
            s = fmaf(p[6], w6, s);
            orow_s[w][q] = s;
        }
    }
    __syncthreads();

    // ---------- Phase 1b: windowed max -> cat_s ----------
    for (int j = t; j < G * CATN; j += NTHR) {
        int g  = j / CATN;
        int jj = j - g * CATN;
        int ci = jj / NOFF;
        int o  = jj - ci * NOFF;
        int st = ci * WINSZ + o;
        float m = orow_s[g][st];
        #pragma unroll
        for (int u = 1; u < WINSZ; ++u) m = fmaxf(m, orow_s[g][st + u]);
        cat_s[g][jj] = m;
    }
    __syncthreads();

    // ---------- Phase 2: h1 = relu(cat @ wA + bA) ----------
    // thread t: 4 output cols (c4), row g, k-half kh. float4 wA loads.
    float4* red = (float4*)&orow_s[0][0];   // 256 * 16 B = 4 KB, aliases dead orow_s
    {
        const int c4 = t & 31;          // n-group: cols 4*c4 .. 4*c4+3
        const int g  = (t >> 5) & 3;    // row
        const int kh = t >> 7;          // k-half: 0 or 1
        const int k0 = kh * (CATN / 2);
        const float* wAp = wA + (size_t)k0 * H1N + 4 * c4;
        const float* cp  = &cat_s[g][k0];
        float4 acc = make_float4(0.f, 0.f, 0.f, 0.f);
        #pragma unroll 4
        for (int k = 0; k < CATN / 2; ++k) {
            const float4 a = *(const float4*)(wAp + (size_t)k * H1N);
            const float  c = cp[k];
            acc.x = fmaf(c, a.x, acc.x);
            acc.y = fmaf(c, a.y, acc.y);
            acc.z = fmaf(c, a.z, acc.z);
            acc.w = fmaf(c, a.w, acc.w);
        }
        red[t] = acc;
    }
    __syncthreads();
    if (t < 128) {
        const int c4 = t & 31;
        const int g  = t >> 5;
        const float4 a = red[t];
        const float4 b = red[t + 128];
        const float4 bias = *(const float4*)(bA + 4 * c4);
        h1_s[g][4 * c4 + 0] = fmaxf(a.x + b.x + bias.x, 0.f);
        h1_s[g][4 * c4 + 1] = fmaxf(a.y + b.y + bias.y, 0.f);
        h1_s[g][4 * c4 + 2] = fmaxf(a.z + b.z + bias.z, 0.f);
        h1_s[g][4 * c4 + 3] = fmaxf(a.w + b.w + bias.w, 0.f);
    }
    __syncthreads();

    // ---------- Phase 3: h2 = relu(h1 @ wB + bB) ----------
    if (t < G * H2N) {
        const int g = t >> 5;
        const int n = t & 31;
        float acc = bB[n];
        #pragma unroll 8
        for (int k = 0; k < H1N; ++k)
            acc = fmaf(h1_s[g][k], wB[k * H2N + n], acc);
        h2_s[g][n] = fmaxf(acc, 0.f);
    }
    __syncthreads();

    // ---------- Phase 4: out = h2 @ wC + bC ----------
    if (t < G * OUTN) {
        const int g = t >> 1;
        const int c = t & 1;
        float acc = bC[c];
        #pragma unroll
        for (int k = 0; k < H2N; ++k)
            acc = fmaf(h2_s[g][k], wC[k * OUTN + c], acc);
        out[(size_t)(b0 + g) * OUTN + c] = acc;
    }
}

extern "C" void kernel_launch(void* const* d_in, const int* in_sizes, int n_in,
                              void* d_out, int out_size, void* d_ws, size_t ws_size,
                              hipStream_t stream) {
    const float* x      = (const float*)d_in[0];
    const float* w_step = (const float*)d_in[1];
    const float* b_step = (const float*)d_in[2];
    const float* wA     = (const float*)d_in[3];
    const float* bA     = (const float*)d_in[4];
    const float* wB     = (const float*)d_in[5];
    const float* bB     = (const float*)d_in[6];
    const float* wC     = (const float*)d_in[7];
    const float* bC     = (const float*)d_in[8];
    float* out = (float*)d_out;

    dim3 grid(NB / G);   // 4096 blocks
    fused_struct3<<<grid, NTHR, 0, stream>>>(
        x, w_step, b_step, wA, bA, wB, bB, wC, bC, out);
}

// Round 3
// 763.395 us; speedup vs baseline: 1.1171x; 1.1171x over previous
//
#include <hip/hip_runtime.h>

#define NB      16384
#define QS      1204
#define QSP     1216          // orow padded (multiple of 16 floats)
#define FD      7
#define ROWF    (QS * FD)     // 8428 floats per batch row
#define NCH     120
#define NOFF    5
#define WINSZ   10
#define CATN    600
#define H1N     128
#define H2N     32
#define OUTN    2
#define G       4             // batch rows per block (one per wave in phase 1)
#define NTHR    256

__global__ __launch_bounds__(NTHR, 5) void fused_struct3(
    const float* __restrict__ x,
    const float* __restrict__ w_step,
    const float* __restrict__ b_step,
    const float* __restrict__ wA,
    const float* __restrict__ bA,
    const float* __restrict__ wB,
    const float* __restrict__ bB,
    const float* __restrict__ wC,
    const float* __restrict__ bC,
    float* __restrict__ out)
{
    // 31.8 KB -> 5 blocks/CU (20 waves/CU)
    __shared__ __align__(16) float orow_s[G][QSP];    // 19456 B; dead after pool, aliased as red4
    __shared__ __align__(16) float cat_s[G][CATN];    //  9600 B
    __shared__ __align__(16) float h1_s[G][H1N];      //  2048 B
    __shared__ __align__(16) float h2_s[G][H2N];      //   512 B

    const int t    = threadIdx.x;
    const int lane = t & 63;
    const int w    = t >> 6;
    const int b0   = blockIdx.x * G;

    const float w0 = w_step[0], w1 = w_step[1], w2 = w_step[2], w3 = w_step[3],
                w4 = w_step[4], w5 = w_step[5], w6 = w_step[6];
    const float bs = b_step[0];

    // ---------- Phase 1a: dot products, float4-vectorized (lane owns 4 q's/iter) ----------
    {
        const float* row = x + (size_t)(b0 + w) * ROWF;
        for (int i = 0; i < 5; ++i) {
            const int q0 = i * 256 + 4 * lane;       // multiple of 4
            if (q0 < QS) {
                const float4* p = (const float4*)(row + q0 * FD);  // 112B-aligned
                const float4 v0 = p[0], v1 = p[1], v2 = p[2], v3 = p[3],
                             v4 = p[4], v5 = p[5], v6 = p[6];
                float s0 = bs, s1 = bs, s2 = bs, s3 = bs;
                s0 = fmaf(v0.x, w0, s0); s0 = fmaf(v0.y, w1, s0); s0 = fmaf(v0.z, w2, s0);
                s0 = fmaf(v0.w, w3, s0); s0 = fmaf(v1.x, w4, s0); s0 = fmaf(v1.y, w5, s0);
                s0 = fmaf(v1.z, w6, s0);
                s1 = fmaf(v1.w, w0, s1); s1 = fmaf(v2.x, w1, s1); s1 = fmaf(v2.y, w2, s1);
                s1 = fmaf(v2.z, w3, s1); s1 = fmaf(v2.w, w4, s1); s1 = fmaf(v3.x, w5, s1);
                s1 = fmaf(v3.y, w6, s1);
                s2 = fmaf(v3.z, w0, s2); s2 = fmaf(v3.w, w1, s2); s2 = fmaf(v4.x, w2, s2);
                s2 = fmaf(v4.y, w3, s2); s2 = fmaf(v4.z, w4, s2); s2 = fmaf(v4.w, w5, s2);
                s2 = fmaf(v5.x, w6, s2);
                s3 = fmaf(v5.y, w0, s3); s3 = fmaf(v5.z, w1, s3); s3 = fmaf(v5.w, w2, s3);
                s3 = fmaf(v6.x, w3, s3); s3 = fmaf(v6.y, w4, s3); s3 = fmaf(v6.z, w5, s3);
                s3 = fmaf(v6.w, w6, s3);
                *(float4*)&orow_s[w][q0] = make_float4(s0, s1, s2, s3);
            }
        }
    }
    __syncthreads();

    // ---------- Phase 1b: sliding max (prefix/suffix), one chunk per work item ----------
    #pragma unroll
    for (int it = 0; it < 2; ++it) {
        const int item = t + it * NTHR;              // 0..479
        if (item < G * NCH) {
            const int g  = item / NCH;
            const int ci = item - g * NCH;
            const float* v = &orow_s[g][ci * WINSZ];
            const float4 a = *(const float4*)(v + 0);
            const float4 b = *(const float4*)(v + 4);
            const float4 c = *(const float4*)(v + 8);
            const float4 d = *(const float4*)(v + 12);   // only .x,.y used; pad safe
            // suffix max over v[0..9]
            float s9 = b.w + c.x - c.x; // placeholder avoid; compute directly:
            s9 = c.y;
            float s8 = fmaxf(c.x, s9);
            float s7 = fmaxf(b.w, s8);
            float s6 = fmaxf(b.z, s7);
            float s5 = fmaxf(b.y, s6);
            float s4 = fmaxf(b.x, s5);
            float s3 = fmaxf(a.w, s4);
            float s2 = fmaxf(a.z, s3);
            float s1 = fmaxf(a.y, s2);
            float s0 = fmaxf(a.x, s1);
            // prefix max over v[10..13]
            const float p10 = c.z;
            const float p11 = fmaxf(p10, c.w);
            const float p12 = fmaxf(p11, d.x);
            const float p13 = fmaxf(p12, d.y);
            float* cp = &cat_s[g][ci * NOFF];
            cp[0] = s0;
            cp[1] = fmaxf(s1, p10);
            cp[2] = fmaxf(s2, p11);
            cp[3] = fmaxf(s3, p12);
            cp[4] = fmaxf(s4, p13);
        }
    }
    __syncthreads();

    // ---------- Phase 2: h1 = relu(cat @ wA + bA); wA covered ONCE per block ----------
    // thread = (c4: 4 cols, kh: k-slice of 76 [last 68]); partials for all 4 rows.
    float4* red4 = (float4*)&orow_s[0][0];           // [kh][c4][g] = 8*32*4 float4 = 16 KB
    {
        const int c4  = t & 31;
        const int kh  = t >> 5;                      // 0..7
        const int k0  = kh * 76;                     // 16B-aligned slice starts
        const int len = (kh == 7) ? 68 : 76;
        const float* wAp = wA + (size_t)k0 * H1N + 4 * c4;
        float4 acc0 = make_float4(0.f, 0.f, 0.f, 0.f);
        float4 acc1 = acc0, acc2 = acc0, acc3 = acc0;
        for (int kb = 0; kb < len; kb += 4) {
            const float4 c0 = *(const float4*)&cat_s[0][k0 + kb];
            const float4 c1 = *(const float4*)&cat_s[1][k0 + kb];
            const float4 c2 = *(const float4*)&cat_s[2][k0 + kb];
            const float4 c3 = *(const float4*)&cat_s[3][k0 + kb];
            #pragma unroll
            for (int r = 0; r < 4; ++r) {
                const float4 a = *(const float4*)(wAp + (size_t)(kb + r) * H1N);
                const float e0 = (r == 0) ? c0.x : (r == 1) ? c0.y : (r == 2) ? c0.z : c0.w;
                const float e1 = (r == 0) ? c1.x : (r == 1) ? c1.y : (r == 2) ? c1.z : c1.w;
                const float e2 = (r == 0) ? c2.x : (r == 1) ? c2.y : (r == 2) ? c2.z : c2.w;
                const float e3 = (r == 0) ? c3.x : (r == 1) ? c3.y : (r == 2) ? c3.z : c3.w;
                acc0.x = fmaf(e0, a.x, acc0.x); acc0.y = fmaf(e0, a.y, acc0.y);
                acc0.z = fmaf(e0, a.z, acc0.z); acc0.w = fmaf(e0, a.w, acc0.w);
                acc1.x = fmaf(e1, a.x, acc1.x); acc1.y = fmaf(e1, a.y, acc1.y);
                acc1.z = fmaf(e1, a.z, acc1.z); acc1.w = fmaf(e1, a.w, acc1.w);
                acc2.x = fmaf(e2, a.x, acc2.x); acc2.y = fmaf(e2, a.y, acc2.y);
                acc2.z = fmaf(e2, a.z, acc2.z); acc2.w = fmaf(e2, a.w, acc2.w);
                acc3.x = fmaf(e3, a.x, acc3.x); acc3.y = fmaf(e3, a.y, acc3.y);
                acc3.z = fmaf(e3, a.z, acc3.z); acc3.w = fmaf(e3, a.w, acc3.w);
            }
        }
        const int base = (kh * 32 + c4) * 4;
        red4[base + 0] = acc0;
        red4[base + 1] = acc1;
        red4[base + 2] = acc2;
        red4[base + 3] = acc3;
    }
    __syncthreads();
    if (t < 128) {
        const int c4r = t >> 2;
        const int g   = t & 3;
        float4 s = red4[(0 * 32 + c4r) * 4 + g];     // lanes read consecutive float4s
        #pragma unroll
        for (int kh = 1; kh < 8; ++kh) {
            const float4 r = red4[(kh * 32 + c4r) * 4 + g];
            s.x += r.x; s.y += r.y; s.z += r.z; s.w += r.w;
        }
        const float4 bias = *(const float4*)(bA + 4 * c4r);
        float4 h;
        h.x = fmaxf(s.x + bias.x, 0.f);
        h.y = fmaxf(s.y + bias.y, 0.f);
        h.z = fmaxf(s.z + bias.z, 0.f);
        h.w = fmaxf(s.w + bias.w, 0.f);
        *(float4*)&h1_s[g][4 * c4r] = h;
    }
    __syncthreads();

    // ---------- Phase 3: h2 = relu(h1 @ wB + bB) ----------
    if (t < G * H2N) {
        const int g = t >> 5;
        const int n = t & 31;
        float acc = bB[n];
        #pragma unroll 8
        for (int k = 0; k < H1N; ++k)
            acc = fmaf(h1_s[g][k], wB[k * H2N + n], acc);
        h2_s[g][n] = fmaxf(acc, 0.f);
    }
    __syncthreads();

    // ---------- Phase 4: out = h2 @ wC + bC ----------
    if (t < G * OUTN) {
        const int g = t >> 1;
        const int c = t & 1;
        float acc = bC[c];
        #pragma unroll
        for (int k = 0; k < H2N; ++k)
            acc = fmaf(h2_s[g][k], wC[k * OUTN + c], acc);
        out[(size_t)(b0 + g) * OUTN + c] = acc;
    }
}

extern "C" void kernel_launch(void* const* d_in, const int* in_sizes, int n_in,
                              void* d_out, int out_size, void* d_ws, size_t ws_size,
                              hipStream_t stream) {
    const float* x      = (const float*)d_in[0];
    const float* w_step = (const float*)d_in[1];
    const float* b_step = (const float*)d_in[2];
    const float* wA     = (const float*)d_in[3];
    const float* bA     = (const float*)d_in[4];
    const float* wB     = (const float*)d_in[5];
    const float* bB     = (const float*)d_in[6];
    const float* wC     = (const float*)d_in[7];
    const float* bC     = (const float*)d_in[8];
    float* out = (float*)d_out;

    dim3 grid(NB / G);   // 4096 blocks
    fused_struct3<<<grid, NTHR, 0, stream>>>(
        x, w_step, b_step, wA, bA, wB, bB, wC, bC, out);
}